// Round 1
// baseline (492.077 us; speedup 1.0000x reference)
//
#include <hip/hip_runtime.h>
#include <hip/hip_bf16.h>
#include <math.h>

#define SEQ 2048
#define BATCH 4
#define DM 512
#define NH 8
#define HD 64
#define HID 2048
#define ROWS (BATCH * SEQ)

typedef __attribute__((ext_vector_type(8))) short short8;
typedef __attribute__((ext_vector_type(4))) float f32x4;

__device__ __forceinline__ short f2bf(float f) {
    unsigned u = __float_as_uint(f);
    u += 0x7fff + ((u >> 16) & 1);   // RNE
    return (short)(u >> 16);
}

// ---------------- weight transpose + cast: W[K][N] fp32 -> Wt[N][K] bf16 ----
__global__ __launch_bounds__(256) void tcast_k(const float* __restrict__ W,
                                               short* __restrict__ Wt,
                                               int K, int N) {
    __shared__ float tile[32][33];
    int tx = threadIdx.x, ty = threadIdx.y;
    int n0 = blockIdx.x * 32, k0 = blockIdx.y * 32;
#pragma unroll
    for (int i = 0; i < 4; ++i)
        tile[ty + i * 8][tx] = W[(size_t)(k0 + ty + i * 8) * N + n0 + tx];
    __syncthreads();
#pragma unroll
    for (int i = 0; i < 4; ++i)
        Wt[(size_t)(n0 + ty + i * 8) * K + k0 + tx] = f2bf(tile[tx][ty + i * 8]);
}

// ---------------- layernorm: fp32 [rows][512] -> bf16, one wave per row -----
__global__ __launch_bounds__(256) void ln_k(const float* __restrict__ X,
                                            const float* __restrict__ g,
                                            const float* __restrict__ bta,
                                            short* __restrict__ Y) {
    int t = threadIdx.x;
    int wv = t >> 6, ln = t & 63;
    size_t row = (size_t)blockIdx.x * 4 + wv;
    const float* xr = X + row * DM;
    float4 v0 = *(const float4*)(xr + ln * 4);
    float4 v1 = *(const float4*)(xr + 256 + ln * 4);
    float s = v0.x + v0.y + v0.z + v0.w + v1.x + v1.y + v1.z + v1.w;
    float q = v0.x * v0.x + v0.y * v0.y + v0.z * v0.z + v0.w * v0.w +
              v1.x * v1.x + v1.y * v1.y + v1.z * v1.z + v1.w * v1.w;
#pragma unroll
    for (int off = 1; off < 64; off <<= 1) {
        s += __shfl_xor(s, off);
        q += __shfl_xor(q, off);
    }
    float mean = s * (1.0f / 512.0f);
    float var = q * (1.0f / 512.0f) - mean * mean;
    float rstd = rsqrtf(var + 1e-5f);
    int c0 = ln * 4, c1 = 256 + ln * 4;
    ushort4 o0, o1;
    o0.x = (unsigned short)f2bf((v0.x - mean) * rstd * g[c0 + 0] + bta[c0 + 0]);
    o0.y = (unsigned short)f2bf((v0.y - mean) * rstd * g[c0 + 1] + bta[c0 + 1]);
    o0.z = (unsigned short)f2bf((v0.z - mean) * rstd * g[c0 + 2] + bta[c0 + 2]);
    o0.w = (unsigned short)f2bf((v0.w - mean) * rstd * g[c0 + 3] + bta[c0 + 3]);
    o1.x = (unsigned short)f2bf((v1.x - mean) * rstd * g[c1 + 0] + bta[c1 + 0]);
    o1.y = (unsigned short)f2bf((v1.y - mean) * rstd * g[c1 + 1] + bta[c1 + 1]);
    o1.z = (unsigned short)f2bf((v1.z - mean) * rstd * g[c1 + 2] + bta[c1 + 2]);
    o1.w = (unsigned short)f2bf((v1.w - mean) * rstd * g[c1 + 3] + bta[c1 + 3]);
    *(ushort4*)((unsigned short*)Y + row * DM + c0) = o0;
    *(ushort4*)((unsigned short*)Y + row * DM + c1) = o1;
}

// ---------------- GEMM: C[M][N] = A[M][K] * Bt[N][K]^T, bf16 MFMA ----------
// EPI 0: bf16 out = C + bias
// EPI 1: bf16 out = gelu_exact(C + bias)
// EPI 2: fp32 out = res + (C + bias) * gamma
template <int EPI>
__global__ __launch_bounds__(256) void gemm_bt(const short* __restrict__ A,
                                               const short* __restrict__ Bt,
                                               const float* __restrict__ bias,
                                               const float* __restrict__ gamma,
                                               const float* __restrict__ res,
                                               void* __restrict__ Cout,
                                               int M, int N, int K) {
    __shared__ short As[128][40];   // +8 pad: 2-way-free bank pattern on b128 reads
    __shared__ short Bs[128][40];
    int t = threadIdx.x;
    int w = t >> 6, ln = t & 63;
    int quad = ln >> 4, l15 = ln & 15;
    int n0 = blockIdx.x * 128, m0 = blockIdx.y * 128;
    int wm = (w & 1) * 64, wn = (w >> 1) * 64;

    int rA0 = t >> 2;             // 0..63
    int cA0 = (t & 3) * 8;        // chunk of 8 bf16

    f32x4 acc[4][4];
#pragma unroll
    for (int i = 0; i < 4; ++i)
#pragma unroll
        for (int j = 0; j < 4; ++j) acc[i][j] = (f32x4){0.f, 0.f, 0.f, 0.f};

    for (int k0 = 0; k0 < K; k0 += 32) {
        float4 av0 = *(const float4*)(A + (size_t)(m0 + rA0) * K + k0 + cA0);
        float4 av1 = *(const float4*)(A + (size_t)(m0 + rA0 + 64) * K + k0 + cA0);
        float4 bv0 = *(const float4*)(Bt + (size_t)(n0 + rA0) * K + k0 + cA0);
        float4 bv1 = *(const float4*)(Bt + (size_t)(n0 + rA0 + 64) * K + k0 + cA0);
        __syncthreads();
        *(float4*)&As[rA0][cA0] = av0;
        *(float4*)&As[rA0 + 64][cA0] = av1;
        *(float4*)&Bs[rA0][cA0] = bv0;
        *(float4*)&Bs[rA0 + 64][cA0] = bv1;
        __syncthreads();
        short8 af[4], bf[4];
#pragma unroll
        for (int mi = 0; mi < 4; ++mi)
            af[mi] = *(const short8*)&As[wm + mi * 16 + l15][quad * 8];
#pragma unroll
        for (int ni = 0; ni < 4; ++ni)
            bf[ni] = *(const short8*)&Bs[wn + ni * 16 + l15][quad * 8];
#pragma unroll
        for (int mi = 0; mi < 4; ++mi)
#pragma unroll
            for (int ni = 0; ni < 4; ++ni)
                acc[mi][ni] = __builtin_amdgcn_mfma_f32_16x16x32_bf16(
                    af[mi], bf[ni], acc[mi][ni], 0, 0, 0);
    }

#pragma unroll
    for (int mi = 0; mi < 4; ++mi) {
#pragma unroll
        for (int ni = 0; ni < 4; ++ni) {
#pragma unroll
            for (int r = 0; r < 4; ++r) {
                int row = m0 + wm + mi * 16 + quad * 4 + r;
                int col = n0 + wn + ni * 16 + l15;
                float v = acc[mi][ni][r] + bias[col];
                if (EPI == 0) {
                    ((short*)Cout)[(size_t)row * N + col] = f2bf(v);
                } else if (EPI == 1) {
                    float gg = 0.5f * v * (1.0f + erff(v * 0.70710678118654752f));
                    ((short*)Cout)[(size_t)row * N + col] = f2bf(gg);
                } else {
                    ((float*)Cout)[(size_t)row * N + col] =
                        fmaf(v, gamma[col], res[(size_t)row * N + col]);
                }
            }
        }
    }
}

// ---------------- flash attention: one block = (b, h, 64-row q-tile) --------
__global__ __launch_bounds__(256) void attn_k(const short* __restrict__ qkv,
                                              const float* __restrict__ bias,
                                              short* __restrict__ Aout) {
    __shared__ short Qs[64][72];
    __shared__ short Ks[64][72];
    __shared__ short Vt[64][72];     // transposed: [d][key]
    __shared__ short Ps[4][16][72];  // per-wave P tile, C-layout -> A-layout hop
    int t = threadIdx.x;
    int w = t >> 6, ln = t & 63, quad = ln >> 4, l15 = ln & 15;
    int idx = blockIdx.x;
    int qt = idx >> 5, bh = idx & 31;
    int h = bh >> 2, b = bh & 3;   // b in low bits: 4 batches sharing bias run adjacent
    int q0 = qt * 64;
    size_t base = (size_t)b * SEQ * 1536;

    {   // stage Q tile
        int r0 = t >> 3, c = (t & 7) * 8;
        *(float4*)&Qs[r0][c] =
            *(const float4*)(qkv + base + (size_t)(q0 + r0) * 1536 + h * 64 + c);
        *(float4*)&Qs[r0 + 32][c] =
            *(const float4*)(qkv + base + (size_t)(q0 + r0 + 32) * 1536 + h * 64 + c);
    }
    __syncthreads();
    short8 aq0 = *(const short8*)&Qs[w * 16 + l15][quad * 8];
    short8 aq1 = *(const short8*)&Qs[w * 16 + l15][32 + quad * 8];

    float m_s[4], l_s[4];
    f32x4 o[4];
#pragma unroll
    for (int r = 0; r < 4; ++r) { m_s[r] = -1e30f; l_s[r] = 0.f; }
#pragma unroll
    for (int db = 0; db < 4; ++db) o[db] = (f32x4){0.f, 0.f, 0.f, 0.f};

    const float sc = 0.125f;  // 1/sqrt(64)
    for (int jt = 0; jt < 32; ++jt) {
        int j0 = jt * 64;
        __syncthreads();
        {   // stage K tile + V tile (transposed)
            int r0 = t >> 3, c = (t & 7) * 8;
            *(float4*)&Ks[r0][c] = *(const float4*)(qkv + base +
                (size_t)(j0 + r0) * 1536 + 512 + h * 64 + c);
            *(float4*)&Ks[r0 + 32][c] = *(const float4*)(qkv + base +
                (size_t)(j0 + r0 + 32) * 1536 + 512 + h * 64 + c);
            int kp = r0;  // 0..31: key pair
            union { float4 f; short8 s; } ua, ub;
            ua.f = *(const float4*)(qkv + base + (size_t)(j0 + 2 * kp) * 1536 + 1024 + h * 64 + c);
            ub.f = *(const float4*)(qkv + base + (size_t)(j0 + 2 * kp + 1) * 1536 + 1024 + h * 64 + c);
#pragma unroll
            for (int j = 0; j < 8; ++j) {
                ushort2 pr;
                pr.x = (unsigned short)ua.s[j];
                pr.y = (unsigned short)ub.s[j];
                *(ushort2*)&Vt[c + j][2 * kp] = pr;
            }
        }
        __syncthreads();
        // S = Q K^T   (wave w owns q rows [w*16, w*16+16))
        f32x4 s[4];
#pragma unroll
        for (int ni = 0; ni < 4; ++ni) {
            s[ni] = (f32x4){0.f, 0.f, 0.f, 0.f};
            short8 bk0 = *(const short8*)&Ks[ni * 16 + l15][quad * 8];
            short8 bk1 = *(const short8*)&Ks[ni * 16 + l15][32 + quad * 8];
            s[ni] = __builtin_amdgcn_mfma_f32_16x16x32_bf16(aq0, bk0, s[ni], 0, 0, 0);
            s[ni] = __builtin_amdgcn_mfma_f32_16x16x32_bf16(aq1, bk1, s[ni], 0, 0, 0);
        }
        // bias + online softmax (row = quad*4+r, col = ni*16+l15)
        const float* bp = bias + (size_t)h * SEQ * SEQ +
                          (size_t)(q0 + w * 16 + quad * 4) * SEQ + j0 + l15;
        float sv[4][4];
#pragma unroll
        for (int r = 0; r < 4; ++r) {
#pragma unroll
            for (int ni = 0; ni < 4; ++ni)
                sv[ni][r] = s[ni][r] * sc + bp[(size_t)r * SEQ + ni * 16];
            float mx = fmaxf(fmaxf(sv[0][r], sv[1][r]), fmaxf(sv[2][r], sv[3][r]));
#pragma unroll
            for (int off = 1; off < 16; off <<= 1) mx = fmaxf(mx, __shfl_xor(mx, off));
            float mn = fmaxf(m_s[r], mx);
            float alpha = __expf(m_s[r] - mn);
            m_s[r] = mn;
            float rs = 0.f;
#pragma unroll
            for (int ni = 0; ni < 4; ++ni) {
                float p = __expf(sv[ni][r] - mn);
                sv[ni][r] = p;
                rs += p;
            }
#pragma unroll
            for (int off = 1; off < 16; off <<= 1) rs += __shfl_xor(rs, off);
            l_s[r] = l_s[r] * alpha + rs;
#pragma unroll
            for (int db = 0; db < 4; ++db) o[db][r] *= alpha;
#pragma unroll
            for (int ni = 0; ni < 4; ++ni)
                Ps[w][quad * 4 + r][ni * 16 + l15] = f2bf(sv[ni][r]);
        }
        __syncthreads();   // P: C-layout writes -> A-layout reads (cross-lane)
        // O += P V
#pragma unroll
        for (int kk = 0; kk < 2; ++kk) {
            short8 ap = *(const short8*)&Ps[w][l15][kk * 32 + quad * 8];
#pragma unroll
            for (int db = 0; db < 4; ++db) {
                short8 bv = *(const short8*)&Vt[db * 16 + l15][kk * 32 + quad * 8];
                o[db] = __builtin_amdgcn_mfma_f32_16x16x32_bf16(ap, bv, o[db], 0, 0, 0);
            }
        }
    }
#pragma unroll
    for (int db = 0; db < 4; ++db)
#pragma unroll
        for (int r = 0; r < 4; ++r) {
            float v = o[db][r] / l_s[r];
            Aout[(size_t)(b * SEQ + q0 + w * 16 + quad * 4 + r) * DM +
                 h * 64 + db * 16 + l15] = f2bf(v);
        }
}

extern "C" void kernel_launch(void* const* d_in, const int* in_sizes, int n_in,
                              void* d_out, int out_size, void* d_ws, size_t ws_size,
                              hipStream_t stream) {
    const float* x      = (const float*)d_in[0];
    const float* bias   = (const float*)d_in[1];
    const float* qkv_w  = (const float*)d_in[2];
    const float* qkv_b  = (const float*)d_in[3];
    const float* out_w  = (const float*)d_in[4];
    const float* out_b  = (const float*)d_in[5];
    const float* ln1_w  = (const float*)d_in[6];
    const float* ln1_b  = (const float*)d_in[7];
    const float* ln2_w  = (const float*)d_in[8];
    const float* ln2_b  = (const float*)d_in[9];
    const float* ffn_w1 = (const float*)d_in[10];
    const float* ffn_b1 = (const float*)d_in[11];
    const float* ffn_w2 = (const float*)d_in[12];
    const float* ffn_b2 = (const float*)d_in[13];
    const float* gamma1 = (const float*)d_in[14];
    const float* gamma2 = (const float*)d_in[15];
    float* out = (float*)d_out;

    // workspace carve-up (bf16 buffers as short*), ~90 MB total
    short* wqkvT = (short*)d_ws;                         // [1536][512]
    short* woutT = wqkvT + (size_t)1536 * 512;           // [512][512]
    short* w1T   = woutT + (size_t)512 * 512;            // [2048][512]
    short* w2T   = w1T + (size_t)2048 * 512;             // [512][2048]
    short* y1    = w2T + (size_t)512 * 2048;             // [8192][512]  (reused as y2)
    short* qkvB  = y1 + (size_t)ROWS * DM;               // [8192][1536]
    short* aoutB = qkvB + (size_t)ROWS * 1536;           // [8192][512]
    float* x1    = (float*)(aoutB + (size_t)ROWS * DM);  // [8192][512] fp32
    short* hB    = qkvB;  // ffn hidden [8192][2048] reuses qkv+aout region (both dead)

    tcast_k<<<dim3(1536 / 32, 512 / 32), dim3(32, 8), 0, stream>>>(qkv_w, wqkvT, 512, 1536);
    tcast_k<<<dim3(512 / 32, 512 / 32), dim3(32, 8), 0, stream>>>(out_w, woutT, 512, 512);
    tcast_k<<<dim3(2048 / 32, 512 / 32), dim3(32, 8), 0, stream>>>(ffn_w1, w1T, 512, 2048);
    tcast_k<<<dim3(512 / 32, 2048 / 32), dim3(32, 8), 0, stream>>>(ffn_w2, w2T, 2048, 512);

    ln_k<<<ROWS / 4, 256, 0, stream>>>(x, ln1_w, ln1_b, y1);
    gemm_bt<0><<<dim3(1536 / 128, ROWS / 128), 256, 0, stream>>>(
        y1, wqkvT, qkv_b, nullptr, nullptr, qkvB, ROWS, 1536, 512);
    attn_k<<<1024, 256, 0, stream>>>(qkvB, bias, aoutB);
    gemm_bt<2><<<dim3(512 / 128, ROWS / 128), 256, 0, stream>>>(
        aoutB, woutT, out_b, gamma1, x, x1, ROWS, 512, 512);
    ln_k<<<ROWS / 4, 256, 0, stream>>>(x1, ln2_w, ln2_b, y1);
    gemm_bt<1><<<dim3(2048 / 128, ROWS / 128), 256, 0, stream>>>(
        y1, w1T, ffn_b1, nullptr, nullptr, hB, ROWS, 2048, 512);
    gemm_bt<2><<<dim3(512 / 128, ROWS / 128), 256, 0, stream>>>(
        hB, w2T, ffn_b2, gamma2, x1, out, ROWS, 512, 2048);
}